// Round 5
// baseline (273.165 us; speedup 1.0000x reference)
//
#include <hip/hip_runtime.h>

#define B_ 2
#define N_ 2048
#define F_ 64
#define C_ 64
#define L_ 4
#define SK 4    // split-K factor over j: 4 blocks/CU for latency decorrelation
#define NJ (N_ / SK)        // 512 j per block
#define TSTEPS (NJ / 32)    // 16 K-steps
#define PJ 40   // padded LDS j-stride (halves): 80 B rows -> 16B-aligned b128 reads, ~2-way banks

typedef _Float16 half8 __attribute__((ext_vector_type(8)));
typedef _Float16 half2 __attribute__((ext_vector_type(2)));
typedef float floatx4 __attribute__((ext_vector_type(4)));

// ---------------------------------------------------------------------------
// K0: V[b][j][f] -> Vth[b][f][j] (fp16), LDS transpose.  (verified R2/R4)
// grid = B * N/64 = 64 blocks, 256 threads
// ---------------------------------------------------------------------------
__global__ __launch_bounds__(256) void k0_transpose(const float* __restrict__ V,
                                                    _Float16* __restrict__ Vth) {
    __shared__ float tile[64][65];
    const int b  = blockIdx.x >> 5;          // 0..1
    const int j0 = (blockIdx.x & 31) * 64;   // j tile base
    const int tid = threadIdx.x;

    const floatx4* V4 = (const floatx4*)(V + ((size_t)(b * N_ + j0)) * F_);
#pragma unroll
    for (int s = 0; s < 4; ++s) {
        int g = tid + 256 * s;               // 0..1023 float4 slots
        int jl = g >> 4;                     // 0..63
        int fq = g & 15;                     // 0..15
        floatx4 v = V4[jl * 16 + fq];
        tile[jl][fq * 4 + 0] = v.x;
        tile[jl][fq * 4 + 1] = v.y;
        tile[jl][fq * 4 + 2] = v.z;
        tile[jl][fq * 4 + 3] = v.w;
    }
    __syncthreads();

    const int f = tid >> 2;                  // 0..63
    const int jb = (tid & 3) * 16;           // 0..48
    _Float16* dh = Vth + ((size_t)(b * F_ + f)) * N_ + j0 + jb;
#pragma unroll
    for (int u = 0; u < 16; u += 4) {
        half2 h01 = {(_Float16)tile[jb + u + 0][f], (_Float16)tile[jb + u + 1][f]};   // RNE
        half2 h23 = {(_Float16)tile[jb + u + 2][f], (_Float16)tile[jb + u + 3][f]};
        *(half2*)(dh + u + 0) = h01;
        *(half2*)(dh + u + 2) = h23;
    }
}

// ---------------------------------------------------------------------------
// K1: fused deg + agg via fp16 MFMA, split-K over j.  Main loop VERBATIM
// round-2/round-4 (hardware-verified).  Epilogue: same index mapping as the
// verified aggT stores, but unsafeAtomicAdd into a single L2-resident
// aggS[b][k][i] (4 MB) / degS[b][l][i] (64 KB) — no split-K partial buffers.
// grid = B * N/16 * SK = 1024 blocks (4/CU), 256 thr (4 waves).
// ---------------------------------------------------------------------------
__global__ __launch_bounds__(256, 4) void k1_agg(const float* __restrict__ A,
                                                 const _Float16* __restrict__ Vth,
                                                 float* __restrict__ aggS,
                                                 float* __restrict__ degS) {
    __shared__ _Float16 lds[2 * 4 * 16 * PJ];   // 10 KB: [buf][l][i][PJ]

    const int bid = blockIdx.x;          // 0..1023
    const int b   = bid >> 9;
    const int rem = bid & 511;
    const int i0  = (rem >> 2) * 16;
    const int p   = rem & 3;             // split-K slice
    const int tid  = threadIdx.x;
    const int w    = tid >> 6;       // wave id == l
    const int lane = tid & 63;
    const int m    = lane & 15;      // A row / B col / C col within tile
    const int q    = lane >> 4;      // quad group

    // staging mapping: thread -> (row i_s, j-pair jp)
    const int i_s = tid >> 4;        // 0..15
    const int jp  = tid & 15;        // 0..15 -> j = 2jp, 2jp+1

    const floatx4* Abase = (const floatx4*)A + ((size_t)(b * N_ + i0 + i_s)) * N_ + p * NJ;
    const _Float16* Vrow = Vth + ((size_t)b * F_) * N_ + p * NJ;

    floatx4 acc0 = {0,0,0,0}, acc1 = {0,0,0,0}, acc2 = {0,0,0,0}, acc3 = {0,0,0,0};
    floatx4 accd = {0,0,0,0};

    half8 bones;                     // B[k][0] = 1 -> col 0 of deg tile = row sums
#pragma unroll
    for (int e = 0; e < 8; ++e) bones[e] = (m == 0) ? (_Float16)1.0f : (_Float16)0.0f;

    floatx4 a_cur0, a_cur1, a_nxt0, a_nxt1;
    half8 v_cur0, v_cur1, v_cur2, v_cur3, v_nxt0, v_nxt1, v_nxt2, v_nxt3;

#define LOAD_A(t, x0, x1) do { int jj = (t) * 32 + 2 * jp; x0 = Abase[jj]; x1 = Abase[jj + 1]; } while (0)
#define LOAD_V(t, v0, v1, v2, v3) do { int jj = (t) * 32 + q * 8;                                  \
        v0 = *(const half8*)(Vrow + (size_t)(0  + m) * N_ + jj);                                   \
        v1 = *(const half8*)(Vrow + (size_t)(16 + m) * N_ + jj);                                   \
        v2 = *(const half8*)(Vrow + (size_t)(32 + m) * N_ + jj);                                   \
        v3 = *(const half8*)(Vrow + (size_t)(48 + m) * N_ + jj); } while (0)

    LOAD_A(0, a_cur0, a_cur1);
    LOAD_V(0, v_cur0, v_cur1, v_cur2, v_cur3);
    LOAD_A(1, a_nxt0, a_nxt1);
    LOAD_V(1, v_nxt0, v_nxt1, v_nxt2, v_nxt3);

#pragma unroll 2
    for (int t = 0; t < TSTEPS; ++t) {
        const int buf = t & 1;
        _Float16* dst = lds + buf * (4 * 16 * PJ);
        {   // fp32 -> fp16 (RNE) + LDS write: lane holds A[i_s][2jp..2jp+1][l=0..3]
            const float* c0 = (const float*)&a_cur0;
            const float* c1 = (const float*)&a_cur1;
#pragma unroll
            for (int l = 0; l < 4; ++l) {
                half2 h = {(_Float16)c0[l], (_Float16)c1[l]};
                *(half2*)(dst + (l * 16 + i_s) * PJ + 2 * jp) = h;
            }
        }
        __syncthreads();

        // rotate prefetch (depth 2: tile t+2 issued now, consumed at iter t+2)
        a_cur0 = a_nxt0; a_cur1 = a_nxt1;
        const int tn = (t + 2 < TSTEPS) ? (t + 2) : (TSTEPS - 1);
        LOAD_A(tn, a_nxt0, a_nxt1);

        // compute: A-frag from LDS plane l=w, B-frags from registers
        half8 af = *(const half8*)(lds + buf * (4 * 16 * PJ) + (w * 16 + m) * PJ + q * 8);
        acc0 = __builtin_amdgcn_mfma_f32_16x16x32_f16(af, v_cur0, acc0, 0, 0, 0);
        acc1 = __builtin_amdgcn_mfma_f32_16x16x32_f16(af, v_cur1, acc1, 0, 0, 0);
        acc2 = __builtin_amdgcn_mfma_f32_16x16x32_f16(af, v_cur2, acc2, 0, 0, 0);
        acc3 = __builtin_amdgcn_mfma_f32_16x16x32_f16(af, v_cur3, acc3, 0, 0, 0);
        accd = __builtin_amdgcn_mfma_f32_16x16x32_f16(af, bones,  accd, 0, 0, 0);

        v_cur0 = v_nxt0; v_cur1 = v_nxt1; v_cur2 = v_nxt2; v_cur3 = v_nxt3;
        LOAD_V(tn, v_nxt0, v_nxt1, v_nxt2, v_nxt3);
    }
#undef LOAD_A
#undef LOAD_V

    // epilogue: C layout col=lane&15 (f), row=q*4+reg (i) — identical mapping
    // to the verified R2/R4 stores, but atomic scalar adds into shared aggS.
    float* aggb = aggS + (size_t)b * 256 * N_;
    const int ibase = i0 + q * 4;
    const size_t k0r = (size_t)(w * 64 + 0  + m) * N_ + ibase;
    const size_t k1r = (size_t)(w * 64 + 16 + m) * N_ + ibase;
    const size_t k2r = (size_t)(w * 64 + 32 + m) * N_ + ibase;
    const size_t k3r = (size_t)(w * 64 + 48 + m) * N_ + ibase;
#pragma unroll
    for (int r = 0; r < 4; ++r) {
        unsafeAtomicAdd(aggb + k0r + r, acc0[r]);
        unsafeAtomicAdd(aggb + k1r + r, acc1[r]);
        unsafeAtomicAdd(aggb + k2r + r, acc2[r]);
        unsafeAtomicAdd(aggb + k3r + r, acc3[r]);
    }
    if (m == 0) {
        float* dg = degS + ((size_t)(b * L_ + w)) * N_ + ibase;
#pragma unroll
        for (int r = 0; r < 4; ++r) unsafeAtomicAdd(dg + r, accd[r]);
    }
}

// ---------------------------------------------------------------------------
// K2: out[b,i,c] = sigmoid(V@w1 + (deg (x) V)@w2 - agg@w3), fp32 VALU.
// Structure identical to verified R4 k2, but phase 1 reads the single
// pre-reduced aggS/degS (no split-K partial sums).
// grid = B * N/4 = 1024 blocks (4/CU, 16 waves/CU), 256 thr.
// ---------------------------------------------------------------------------
__global__ __launch_bounds__(256) void k2_out(const float* __restrict__ V,
                                              const float* __restrict__ degS,
                                              const float* __restrict__ aggS,
                                              const float* __restrict__ w1,
                                              const float* __restrict__ w2,
                                              const float* __restrict__ w3,
                                              float* __restrict__ out) {
    __shared__ float xsum[256][4];   // [k][i_loc]
    __shared__ float vt[4][64];      // [i_loc][f]
    __shared__ float dsum[4][4];     // [l][i_loc]

    const int raw = blockIdx.x;      // 0..1023
    const int b   = raw >> 9;
    const int t9  = raw & 511;
    // XCD swizzle: consecutive-i tiles land on the same XCD (L2 line sharing).
    const int tile = ((t9 & 7) << 6) | (t9 >> 3);
    const int i0  = tile * 4;
    const int tid = threadIdx.x;

    // phase 1a: xsum[k][0..3] = aggS[b][k][i0..i0+3]  (single buffer now)
    {
        const int k = tid;
        *(floatx4*)&xsum[k][0] = *(const floatx4*)(aggS + ((size_t)b * 256 + k) * N_ + i0);
    }
    // phase 1b: vt[i_loc][f] (coalesced 1 KB)
    {
        const int il = tid >> 6, f = tid & 63;
        vt[il][f] = V[((size_t)(b * N_ + i0 + il)) * F_ + f];
    }
    // phase 1c: dsum[l][i_loc]
    if (tid < 16) {
        const int l = tid >> 2, il = tid & 3;
        dsum[l][il] = degS[((size_t)(b * L_ + l)) * N_ + i0 + il];
    }
    __syncthreads();

    // phase 2: one thread per (i_loc, c); wave = one i row (LDS reads broadcast)
    const int il = tid >> 6;
    const int c  = tid & 63;
    const float d0 = dsum[0][il], d1 = dsum[1][il], d2 = dsum[2][il], d3 = dsum[3][il];

    float acc = 0.0f;
#pragma unroll 4
    for (int f = 0; f < 64; ++f) {
        const float x = vt[il][f];
        acc += x        * w1[f * 64 + c];
        acc += (d0 * x) * w2[(0 * 64 + f) * 64 + c];
        acc += (d1 * x) * w2[(1 * 64 + f) * 64 + c];
        acc += (d2 * x) * w2[(2 * 64 + f) * 64 + c];
        acc += (d3 * x) * w2[(3 * 64 + f) * 64 + c];
    }
#pragma unroll 4
    for (int k = 0; k < 256; ++k) {
        acc -= xsum[k][il] * w3[k * 64 + c];
    }

    out[((size_t)(b * N_ + i0 + il)) * C_ + c] = 1.0f / (1.0f + __expf(-acc));
}

// ---------------------------------------------------------------------------
extern "C" void kernel_launch(void* const* d_in, const int* in_sizes, int n_in,
                              void* d_out, int out_size, void* d_ws, size_t ws_size,
                              hipStream_t stream) {
    const float* V  = (const float*)d_in[0];
    const float* A  = (const float*)d_in[1];
    const float* w1 = (const float*)d_in[2];
    const float* w2 = (const float*)d_in[3];
    const float* w3 = (const float*)d_in[4];
    float* out = (float*)d_out;

    char* ws = (char*)d_ws;
    float*    aggS = (float*)(ws);                  // B*256*N*4 = 4 MB
    float*    degS = (float*)(ws + 4194304);        // B*L*N*4   = 64 KB
    _Float16* Vth  = (_Float16*)(ws + 4259840);     // B*F*N*2   = 512 KB

    // zero the atomic accumulators (ws is re-poisoned 0xAA before every call);
    // hipMemsetAsync is graph-capture-safe. 4 MB + 64 KB contiguous.
    hipMemsetAsync(ws, 0, 4259840, stream);

    hipLaunchKernelGGL(k0_transpose, dim3(B_ * (N_ / 64)), dim3(256), 0, stream, V, Vth);
    hipLaunchKernelGGL(k1_agg,       dim3(B_ * (N_ / 16) * SK), dim3(256), 0, stream,
                       A, Vth, aggS, degS);
    hipLaunchKernelGGL(k2_out,       dim3(B_ * (N_ / 4)), dim3(256), 0, stream,
                       V, degS, aggS, w1, w2, w3, out);
}

// Round 6
// 258.578 us; speedup vs baseline: 1.0564x; 1.0564x over previous
//
#include <hip/hip_runtime.h>

#define B_ 2
#define N_ 2048
#define F_ 64
#define C_ 64
#define L_ 4
#define SP 8    // j-partials: 8 slices of 256 j each

typedef _Float16 half8 __attribute__((ext_vector_type(8)));
typedef _Float16 half2 __attribute__((ext_vector_type(2)));
typedef float floatx4 __attribute__((ext_vector_type(4)));

// ---------------------------------------------------------------------------
// K0: V[b][j][f] -> Vth[b][f][j] (fp16), LDS transpose.  (verified R2/R4/R5)
// grid = B * N/64 = 64 blocks, 256 threads
// ---------------------------------------------------------------------------
__global__ __launch_bounds__(256) void k0_transpose(const float* __restrict__ V,
                                                    _Float16* __restrict__ Vth) {
    __shared__ float tile[64][65];
    const int b  = blockIdx.x >> 5;          // 0..1
    const int j0 = (blockIdx.x & 31) * 64;   // j tile base
    const int tid = threadIdx.x;

    const floatx4* V4 = (const floatx4*)(V + ((size_t)(b * N_ + j0)) * F_);
#pragma unroll
    for (int s = 0; s < 4; ++s) {
        int g = tid + 256 * s;               // 0..1023 float4 slots
        int jl = g >> 4;                     // 0..63
        int fq = g & 15;                     // 0..15
        floatx4 v = V4[jl * 16 + fq];
        tile[jl][fq * 4 + 0] = v.x;
        tile[jl][fq * 4 + 1] = v.y;
        tile[jl][fq * 4 + 2] = v.z;
        tile[jl][fq * 4 + 3] = v.w;
    }
    __syncthreads();

    const int f = tid >> 2;                  // 0..63
    const int jb = (tid & 3) * 16;           // 0..48
    _Float16* dh = Vth + ((size_t)(b * F_ + f)) * N_ + j0 + jb;
#pragma unroll
    for (int u = 0; u < 16; u += 4) {
        half2 h01 = {(_Float16)tile[jb + u + 0][f], (_Float16)tile[jb + u + 1][f]};   // RNE
        half2 h23 = {(_Float16)tile[jb + u + 2][f], (_Float16)tile[jb + u + 3][f]};
        *(half2*)(dh + u + 0) = h01;
        *(half2*)(dh + u + 2) = h23;
    }
}

// ---------------------------------------------------------------------------
// K1: deg + agg via fp16 MFMA — BARRIER-FREE, no LDS.
// grid = B * (N/16) * 2 = 512 blocks (2/CU), 256 thr (4 waves).
// Wave w handles ALL 4 edge types for j-slice p = h*4+w (256 j, 8 K-steps).
// Lane (m,q) loads A[i0+m][j][0..3] as full dwordx4 (every fetched byte used),
// converts fp32->fp16 in-register (RNE), feeds 4 A-frags (one per l).
// No __syncthreads -> no vmcnt(0) convoy; 8 waves/CU keep HBM queue full.
// Epilogue: verified C-layout float4 stores to aggT[p][b][k][i], degT[p][b][l][i].
// ---------------------------------------------------------------------------
__global__ __launch_bounds__(256, 2) void k1_agg(const float* __restrict__ A,
                                                 const _Float16* __restrict__ Vth,
                                                 float* __restrict__ aggT,
                                                 float* __restrict__ degT) {
    const int bid = blockIdx.x;          // 0..511
    const int b   = bid >> 8;
    const int rem = bid & 255;
    const int i0  = (rem >> 1) * 16;
    const int h   = rem & 1;             // j-half of this block
    const int tid  = threadIdx.x;
    const int w    = tid >> 6;           // wave id -> j-eighth within half
    const int lane = tid & 63;
    const int m    = lane & 15;          // MFMA row (i) / B col (f)
    const int q    = lane >> 4;          // quad group (k-octet / C row group)
    const int p    = h * 4 + w;          // partial slice 0..7
    const int jwin = p * 256;            // this wave's j window

    // A row for lane's i = i0+m: one float4 per j (the 4 l's)
    const floatx4* Arow = (const floatx4*)(A + (((size_t)(b * N_ + i0 + m)) * N_ + jwin) * 4);
    const _Float16* Vrow = Vth + ((size_t)b * F_) * N_ + jwin;

    floatx4 acc[4][4];                   // [l][f-chunk]
    floatx4 accd[4];                     // deg per l
#pragma unroll
    for (int l = 0; l < 4; ++l) {
        accd[l] = (floatx4){0, 0, 0, 0};
#pragma unroll
        for (int fc = 0; fc < 4; ++fc) acc[l][fc] = (floatx4){0, 0, 0, 0};
    }

    half8 bones;                         // B[k][0]=1 -> C col 0 = row sums (deg)
#pragma unroll
    for (int e = 0; e < 8; ++e) bones[e] = (m == 0) ? (_Float16)1.0f : (_Float16)0.0f;

    half8 v_cur[4], v_nxt[4];
#pragma unroll
    for (int fc = 0; fc < 4; ++fc)
        v_cur[fc] = *(const half8*)(Vrow + (size_t)(fc * 16 + m) * N_ + q * 8);

#pragma unroll 2
    for (int t = 0; t < 8; ++t) {
        // A loads for this step: 8 consecutive float4 (j = t*32 + q*8 .. +7)
        floatx4 a[8];
        const int jb = t * 32 + q * 8;
#pragma unroll
        for (int e = 0; e < 8; ++e) a[e] = Arow[jb + e];

        // V prefetch for next step (clamped; last-step reload is harmless)
        const int tn = (t < 7) ? t + 1 : 7;
        const int jn = tn * 32 + q * 8;
#pragma unroll
        for (int fc = 0; fc < 4; ++fc)
            v_nxt[fc] = *(const half8*)(Vrow + (size_t)(fc * 16 + m) * N_ + jn);

        // fp32 -> fp16 (RNE) in-register: frag f[l][e] = A[i=m][j=jb+e][l]
        half8 f[4];
#pragma unroll
        for (int l = 0; l < 4; ++l) {
#pragma unroll
            for (int e = 0; e < 8; ++e) f[l][e] = (_Float16)a[e][l];
        }

        // 20 MFMAs: 4 l x 4 f-chunks + 4 deg
#pragma unroll
        for (int l = 0; l < 4; ++l) {
            acc[l][0] = __builtin_amdgcn_mfma_f32_16x16x32_f16(f[l], v_cur[0], acc[l][0], 0, 0, 0);
            acc[l][1] = __builtin_amdgcn_mfma_f32_16x16x32_f16(f[l], v_cur[1], acc[l][1], 0, 0, 0);
            acc[l][2] = __builtin_amdgcn_mfma_f32_16x16x32_f16(f[l], v_cur[2], acc[l][2], 0, 0, 0);
            acc[l][3] = __builtin_amdgcn_mfma_f32_16x16x32_f16(f[l], v_cur[3], acc[l][3], 0, 0, 0);
            accd[l]   = __builtin_amdgcn_mfma_f32_16x16x32_f16(f[l], bones,    accd[l],   0, 0, 0);
        }
#pragma unroll
        for (int fc = 0; fc < 4; ++fc) v_cur[fc] = v_nxt[fc];
    }

    // epilogue: verified C layout (col=lane&15 -> f, row=q*4+r -> i), float4 stores
    float* aggb = aggT + ((size_t)(p * B_ + b)) * 256 * N_;
    const int ibase = i0 + q * 4;
#pragma unroll
    for (int l = 0; l < 4; ++l) {
#pragma unroll
        for (int fc = 0; fc < 4; ++fc) {
            const int k = l * 64 + fc * 16 + m;
            *(floatx4*)(aggb + (size_t)k * N_ + ibase) = acc[l][fc];
        }
    }
    if (m == 0) {
#pragma unroll
        for (int l = 0; l < 4; ++l)
            *(floatx4*)(degT + ((size_t)((p * B_ + b) * L_ + l)) * N_ + ibase) = accd[l];
    }
}

// ---------------------------------------------------------------------------
// K2: out[b,i,c] = sigmoid(V@w1 + (deg (x) V)@w2 - agg@w3), fp32 VALU.
// Verbatim R4 structure (hardware-verified), now summing SP=8 partials.
// grid = B * N/4 = 1024 blocks, 256 thr; block = 4 i-rows x 64 c.
// ---------------------------------------------------------------------------
__global__ __launch_bounds__(256) void k2_out(const float* __restrict__ V,
                                              const float* __restrict__ degT,
                                              const float* __restrict__ aggT,
                                              const float* __restrict__ w1,
                                              const float* __restrict__ w2,
                                              const float* __restrict__ w3,
                                              float* __restrict__ out) {
    __shared__ float xsum[256][4];   // [k][i_loc]  summed agg partials
    __shared__ float vt[4][64];      // [i_loc][f]
    __shared__ float dsum[4][4];     // [l][i_loc]  summed deg partials

    const int raw = blockIdx.x;      // 0..1023
    const int b   = raw >> 9;
    const int t9  = raw & 511;
    // XCD swizzle: consecutive-i tiles land on the same XCD (L2 line sharing).
    const int tile = ((t9 & 7) << 6) | (t9 >> 3);
    const int i0  = tile * 4;
    const int tid = threadIdx.x;

    // phase 1a: xsum[k][0..3] = sum_p aggT[p][b][k][i0..i0+3]
    {
        const int k = tid;
        const float* g = aggT + ((size_t)b * 256 + k) * N_ + i0;
        const size_t PS = (size_t)B_ * 256 * N_;
        floatx4 s = *(const floatx4*)(g);
#pragma unroll
        for (int pp = 1; pp < SP; ++pp) s += *(const floatx4*)(g + pp * PS);
        *(floatx4*)&xsum[k][0] = s;
    }
    // phase 1b: vt[i_loc][f] (coalesced 1 KB)
    {
        const int il = tid >> 6, f = tid & 63;
        vt[il][f] = V[((size_t)(b * N_ + i0 + il)) * F_ + f];
    }
    // phase 1c: dsum[l][i_loc]
    if (tid < 16) {
        const int l = tid >> 2, il = tid & 3;
        float s = 0.0f;
#pragma unroll
        for (int pp = 0; pp < SP; ++pp)
            s += degT[((size_t)((pp * B_ + b) * L_ + l)) * N_ + i0 + il];
        dsum[l][il] = s;
    }
    __syncthreads();

    // phase 2: one thread per (i_loc, c); wave = one i row (LDS reads broadcast)
    const int il = tid >> 6;
    const int c  = tid & 63;
    const float d0 = dsum[0][il], d1 = dsum[1][il], d2 = dsum[2][il], d3 = dsum[3][il];

    float acc = 0.0f;
#pragma unroll 4
    for (int f = 0; f < 64; ++f) {
        const float x = vt[il][f];
        acc += x        * w1[f * 64 + c];
        acc += (d0 * x) * w2[(0 * 64 + f) * 64 + c];
        acc += (d1 * x) * w2[(1 * 64 + f) * 64 + c];
        acc += (d2 * x) * w2[(2 * 64 + f) * 64 + c];
        acc += (d3 * x) * w2[(3 * 64 + f) * 64 + c];
    }
#pragma unroll 4
    for (int k = 0; k < 256; ++k) {
        acc -= xsum[k][il] * w3[k * 64 + c];
    }

    out[((size_t)(b * N_ + i0 + il)) * C_ + c] = 1.0f / (1.0f + __expf(-acc));
}

// ---------------------------------------------------------------------------
extern "C" void kernel_launch(void* const* d_in, const int* in_sizes, int n_in,
                              void* d_out, int out_size, void* d_ws, size_t ws_size,
                              hipStream_t stream) {
    const float* V  = (const float*)d_in[0];
    const float* A  = (const float*)d_in[1];
    const float* w1 = (const float*)d_in[2];
    const float* w2 = (const float*)d_in[3];
    const float* w3 = (const float*)d_in[4];
    float* out = (float*)d_out;

    char* ws = (char*)d_ws;
    float*    aggT = (float*)(ws);                  // SP*B*256*N*4 = 32 MB
    float*    degT = (float*)(ws + 33554432);       // SP*B*L*N*4   = 512 KB
    _Float16* Vth  = (_Float16*)(ws + 34078720);    // B*F*N*2      = 512 KB

    hipLaunchKernelGGL(k0_transpose, dim3(B_ * (N_ / 64)), dim3(256), 0, stream, V, Vth);
    hipLaunchKernelGGL(k1_agg,       dim3(B_ * (N_ / 16) * 2), dim3(256), 0, stream,
                       A, Vth, aggT, degT);
    hipLaunchKernelGGL(k2_out,       dim3(B_ * (N_ / 4)), dim3(256), 0, stream,
                       V, degT, aggT, w1, w2, w3, out);
}

// Round 7
// 252.726 us; speedup vs baseline: 1.0809x; 1.0232x over previous
//
#include <hip/hip_runtime.h>

#define B_ 2
#define N_ 2048
#define F_ 64
#define C_ 64
#define L_ 4
#define K_ (N_ * L_)      // 8192: GEMM K dim, A natural flat layout k = j*4+l
#define PCOLS 80          // P row: cols 0..63 = -term3, 64..67 = deg, 68..79 = 0
#define SKB 4             // P partial slices (one per block covering an i-tile)

typedef _Float16 half8 __attribute__((ext_vector_type(8)));
typedef _Float16 half4 __attribute__((ext_vector_type(4)));
typedef float floatx4 __attribute__((ext_vector_type(4)));

// ---------------------------------------------------------------------------
// K0: WbigT[b][c][j*4+l] = fp16( - sum_f V[b,j,f] * w3[l*64+f][c] )
// grid = B * N/4 = 1024 blocks, 256 thr = (jl 0..3, c 0..63).
// w3 reads coalesced over c (verified R4 pattern); 8-B half4 stores.
// ---------------------------------------------------------------------------
__global__ __launch_bounds__(256) void k0_wbig(const float* __restrict__ V,
                                               const float* __restrict__ w3,
                                               _Float16* __restrict__ WbigT) {
    __shared__ float vt[4][64];
    const int bid = blockIdx.x;
    const int b   = bid >> 9;
    const int j0  = (bid & 511) * 4;
    const int tid = threadIdx.x;
    const int jl  = tid >> 6;
    const int c   = tid & 63;

    vt[jl][c] = V[((size_t)(b * N_ + j0 + jl)) * F_ + c];
    __syncthreads();

    half4 h;
#pragma unroll
    for (int l = 0; l < 4; ++l) {
        float s = 0.0f;
#pragma unroll 8
        for (int f = 0; f < 64; ++f)
            s += vt[jl][f] * w3[(l * 64 + f) * 64 + c];
        h[l] = (_Float16)(-s);          // negated: GEMM directly yields -term3
    }
    *(half4*)(WbigT + ((size_t)(b * 64 + c)) * K_ + (size_t)(j0 + jl) * 4) = h;
}

// ---------------------------------------------------------------------------
// K1: P[skb][b][i][0..79] partial GEMM  A[b,i,:] x [WbigT | bind]  over a
// 2048-k slice (4 waves x 512 k), fp16 MFMA 16x16x32.
// grid = (B*N/16) * SKB = 1024 blocks (4/CU, 4 waves/SIMD), 256 thr.
// Depth-2 register prefetch on BOTH A (HBM) and B (L2) — no per-step barrier;
// one end barrier LDS-reduces the 4 waves' k-slices.
// Fragment mappings: A[m][q*8+e], B[k=q*8+e][col=m], C col=m,row=q*4+r (verified).
// ---------------------------------------------------------------------------
__global__ __launch_bounds__(256, 4) void k1_gemm(const float* __restrict__ A,
                                                  const _Float16* __restrict__ WbigT,
                                                  float* __restrict__ P) {
    __shared__ float red[4][16][84];     // [wave][i][c] (+4 pad: breaks 4-way bank alias)

    const int bid  = blockIdx.x;         // 0..1023
    const int skb  = bid & 3;
    const int tile = bid >> 2;
    const int b    = tile >> 7;
    const int i0   = (tile & 127) * 16;
    const int tid  = threadIdx.x;
    const int w    = tid >> 6;
    const int lane = tid & 63;
    const int m    = lane & 15;
    const int q    = lane >> 4;

    const int kw = (skb * 4 + w) * 512;  // this wave's k window (512 k, 16 steps)

    const float* Ap = A + ((size_t)(b * N_ + i0 + m)) * K_ + kw + q * 8;
    const _Float16* Bp = WbigT + ((size_t)b * 64 + m) * K_ + kw + q * 8;

    floatx4 acc[5];
#pragma unroll
    for (int fc = 0; fc < 5; ++fc) acc[fc] = (floatx4){0, 0, 0, 0};

    half8 bind;                          // constant deg tile: col 64+m <- k%4 == m
#pragma unroll
    for (int e = 0; e < 8; ++e) bind[e] = (m == (e & 3)) ? (_Float16)1.0f : (_Float16)0.0f;

    floatx4 ac0, ac1, an0, an1;
    half8 bc[4], bn[4];

    ac0 = *(const floatx4*)(Ap + 0);
    ac1 = *(const floatx4*)(Ap + 4);
#pragma unroll
    for (int fc = 0; fc < 4; ++fc) bc[fc] = *(const half8*)(Bp + (size_t)(fc * 16) * K_);

#pragma unroll 2
    for (int t = 0; t < 16; ++t) {
        const int tn = (t < 15) ? t + 1 : 15;     // clamped prefetch
        an0 = *(const floatx4*)(Ap + tn * 32 + 0);
        an1 = *(const floatx4*)(Ap + tn * 32 + 4);
#pragma unroll
        for (int fc = 0; fc < 4; ++fc)
            bn[fc] = *(const half8*)(Bp + (size_t)(fc * 16) * K_ + tn * 32);

        half8 af;                        // fp32 -> fp16 RNE, in-register
#pragma unroll
        for (int e = 0; e < 4; ++e) { af[e] = (_Float16)ac0[e]; af[e + 4] = (_Float16)ac1[e]; }

        acc[0] = __builtin_amdgcn_mfma_f32_16x16x32_f16(af, bc[0], acc[0], 0, 0, 0);
        acc[1] = __builtin_amdgcn_mfma_f32_16x16x32_f16(af, bc[1], acc[1], 0, 0, 0);
        acc[2] = __builtin_amdgcn_mfma_f32_16x16x32_f16(af, bc[2], acc[2], 0, 0, 0);
        acc[3] = __builtin_amdgcn_mfma_f32_16x16x32_f16(af, bc[3], acc[3], 0, 0, 0);
        acc[4] = __builtin_amdgcn_mfma_f32_16x16x32_f16(af, bind,  acc[4], 0, 0, 0);

        ac0 = an0; ac1 = an1;
#pragma unroll
        for (int fc = 0; fc < 4; ++fc) bc[fc] = bn[fc];
    }

    // stash C tiles: col = fc*16+m, row(i) = q*4+r  (verified layout)
#pragma unroll
    for (int fc = 0; fc < 5; ++fc) {
#pragma unroll
        for (int r = 0; r < 4; ++r)
            red[w][q * 4 + r][fc * 16 + m] = acc[fc][r];
    }
    __syncthreads();

    // reduce the 4 waves' k-slices and store P[skb][b][i0+i][c]
    float* Pb = P + (((size_t)(skb * B_ + b)) * N_ + i0) * PCOLS;
#pragma unroll
    for (int s = 0; s < 5; ++s) {
        const int idx = tid + 256 * s;       // 0..1279 over 16 i x 80 c
        const int i   = idx / PCOLS;
        const int c   = idx % PCOLS;
        float v = red[0][i][c] + red[1][i][c] + red[2][i][c] + red[3][i][c];
        Pb[(size_t)i * PCOLS + c] = v;
    }
}

// ---------------------------------------------------------------------------
// K2: out[b,i,c] = sigmoid(V@w1 + sum_l deg_l*(V@w2_l) + P[c])  (P already -term3)
// R4-verified structure; phase 1 sums the SKB P-partials (80 cols).
// grid = B * N/4 = 1024 blocks, 256 thr; block = 4 i x 64 c.
// ---------------------------------------------------------------------------
__global__ __launch_bounds__(256) void k2_out(const float* __restrict__ V,
                                              const float* __restrict__ P,
                                              const float* __restrict__ w1,
                                              const float* __restrict__ w2,
                                              float* __restrict__ out) {
    __shared__ float xsum[4][PCOLS];     // [i_loc][c]  summed P partials
    __shared__ float vt[4][64];          // [i_loc][f]

    const int raw = blockIdx.x;          // 0..1023
    const int b   = raw >> 9;
    const int t9  = raw & 511;
    const int tile = ((t9 & 7) << 6) | (t9 >> 3);   // XCD swizzle (bijection)
    const int i0  = tile * 4;
    const int tid = threadIdx.x;

    // phase 1a: xsum[il][c] = sum_sk P[sk][b][i0+il][c]   (80 threads, float4)
    if (tid < 80) {
        const int il = tid / 20, c4 = tid % 20;
        const size_t PS = (size_t)B_ * N_ * PCOLS;
        const float* g = P + ((size_t)b * N_ + i0 + il) * PCOLS + c4 * 4;
        floatx4 s = *(const floatx4*)(g);
#pragma unroll
        for (int sk = 1; sk < SKB; ++sk) s += *(const floatx4*)(g + sk * PS);
        *(floatx4*)&xsum[il][c4 * 4] = s;
    }
    // phase 1b: vt[i_loc][f] (coalesced 1 KB)
    {
        const int il = tid >> 6, f = tid & 63;
        vt[il][f] = V[((size_t)(b * N_ + i0 + il)) * F_ + f];
    }
    __syncthreads();

    // phase 2: thread = (i_loc, c)
    const int il = tid >> 6;
    const int c  = tid & 63;
    const float d0 = xsum[il][64], d1 = xsum[il][65], d2 = xsum[il][66], d3 = xsum[il][67];

    float acc = xsum[il][c];             // -term3, pre-summed
#pragma unroll 4
    for (int f = 0; f < 64; ++f) {
        const float x = vt[il][f];
        acc += x        * w1[f * 64 + c];
        acc += (d0 * x) * w2[(0 * 64 + f) * 64 + c];
        acc += (d1 * x) * w2[(1 * 64 + f) * 64 + c];
        acc += (d2 * x) * w2[(2 * 64 + f) * 64 + c];
        acc += (d3 * x) * w2[(3 * 64 + f) * 64 + c];
    }

    out[((size_t)(b * N_ + i0 + il)) * C_ + c] = 1.0f / (1.0f + __expf(-acc));
}

// ---------------------------------------------------------------------------
extern "C" void kernel_launch(void* const* d_in, const int* in_sizes, int n_in,
                              void* d_out, int out_size, void* d_ws, size_t ws_size,
                              hipStream_t stream) {
    const float* V  = (const float*)d_in[0];
    const float* A  = (const float*)d_in[1];
    const float* w1 = (const float*)d_in[2];
    const float* w2 = (const float*)d_in[3];
    const float* w3 = (const float*)d_in[4];
    float* out = (float*)d_out;

    char* ws = (char*)d_ws;
    _Float16* WbigT = (_Float16*)(ws);              // B*64*K_*2  = 2 MB
    float*    P     = (float*)(ws + 2097152);       // SKB*B*N*80*4 = 5.24 MB

    hipLaunchKernelGGL(k0_wbig, dim3(B_ * (N_ / 4)), dim3(256), 0, stream, V, w3, WbigT);
    hipLaunchKernelGGL(k1_gemm, dim3((B_ * (N_ / 16)) * SKB), dim3(256), 0, stream,
                       A, WbigT, P);
    hipLaunchKernelGGL(k2_out,  dim3(B_ * (N_ / 4)), dim3(256), 0, stream,
                       V, P, w1, w2, out);
}